// Round 10
// baseline (524.527 us; speedup 1.0000x reference)
//
#include <hip/hip_runtime.h>
#include <hip/hip_fp16.h>
#include <float.h>

#define K1E 6528   // edges per k_split block (13KB u32 stage + 4KB counters in LDS)

__device__ __forceinline__ float wredmax(float v){
#pragma unroll
  for (int m = 32; m >= 1; m >>= 1) v = fmaxf(v, __shfl_xor(v, m, 64));
  return v;
}
__device__ __forceinline__ float wredsum(float v){
#pragma unroll
  for (int m = 32; m >= 1; m >>= 1) v += __shfl_xor(v, m, 64);
  return v;
}
__device__ __forceinline__ int wredsumi(int v){
#pragma unroll
  for (int m = 32; m >= 1; m >>= 1) v += __shfl_xor(v, m, 64);
  return v;
}
__device__ __forceinline__ unsigned pk2(float a, float b){
  __half2 t = __floats2half2_rn(a, b);
  return __builtin_bit_cast(unsigned, t);
}
__device__ __forceinline__ float2 upk2(unsigned u){
  return __half22float2(__builtin_bit_cast(__half2, u));
}

// ---------------- CSR build: deterministic two-level counting sort ----------------
__global__ __launch_bounds__(256) void k_split(
    const int* __restrict__ ei, int E0, int total, int NB, int C1,
    unsigned* __restrict__ temp, int* __restrict__ tcounts, int* __restrict__ trunstart)
{
  __shared__ int cnt[512];
  __shared__ int pref[512];
  __shared__ unsigned stage[K1E];
  const int tid = threadIdx.x, blk = blockIdx.x;
  const int lo = blk * K1E, hi = min(lo + K1E, total);

  for (int i = tid; i < 512; i += 256) cnt[i] = 0;
  __syncthreads();
  for (int i = lo + tid; i < hi; i += 256){
    int d = (i < E0) ? ei[E0 + i] : (i - E0);
    atomicAdd(&cnt[d >> 8], 1);
  }
  __syncthreads();
  for (int i = tid; i < 512; i += 256) pref[i] = cnt[i];
  __syncthreads();
  for (int off = 1; off < 512; off <<= 1){
    int a0 = (tid >= off) ? pref[tid - off] : 0;
    int a1 = pref[tid + 256 - off];
    __syncthreads();
    pref[tid] += a0;
    pref[tid + 256] += a1;
    __syncthreads();
  }
  for (int i = tid; i < NB; i += 256){
    int c = cnt[i];
    int ex = pref[i] - c;
    tcounts[(size_t)i * C1 + blk] = c;
    trunstart[(size_t)i * C1 + blk] = ex;
    cnt[i] = ex;
  }
  __syncthreads();
  for (int i = lo + tid; i < hi; i += 256){
    int s, d;
    if (i < E0){ s = ei[i]; d = ei[E0 + i]; } else { s = i - E0; d = s; }
    int p = atomicAdd(&cnt[d >> 8], 1);
    stage[p] = ((unsigned)(d & 255) << 17) | (unsigned)s;
  }
  __syncthreads();
  for (int i = tid; i < hi - lo; i += 256) temp[(size_t)lo + i] = stage[i];
}

__global__ __launch_bounds__(256) void k_rowsum(
    const int* __restrict__ tcounts, int C1, int* __restrict__ totals)
{
  const int b = blockIdx.x;
  const int* row = tcounts + (size_t)b * C1;
  int s = 0;
  for (int k = threadIdx.x; k < C1; k += 256) s += row[k];
  s = wredsumi(s);
  __shared__ int ws[4];
  if ((threadIdx.x & 63) == 0) ws[threadIdx.x >> 6] = s;
  __syncthreads();
  if (threadIdx.x == 0) totals[b] = ws[0] + ws[1] + ws[2] + ws[3];
}

__global__ __launch_bounds__(512) void k_bases2(
    const int* __restrict__ totals, int NB, int total,
    int* __restrict__ bases, int* __restrict__ offs, int N)
{
  __shared__ int sc[512];
  const int t = threadIdx.x;
  int v = (t < NB) ? totals[t] : 0;
  sc[t] = v; __syncthreads();
  for (int off = 1; off < 512; off <<= 1){
    int a = (t >= off) ? sc[t - off] : 0;
    __syncthreads();
    sc[t] += a;
    __syncthreads();
  }
  if (t < NB) bases[t] = sc[t] - v;
  if (t == 0) offs[N] = total;
}

__global__ __launch_bounds__(512) void k_bucket(
    const unsigned* __restrict__ temp, const int* __restrict__ tcounts,
    const int* __restrict__ trunstart, const int* __restrict__ bases,
    int C1, int N, int* __restrict__ ssrc, int* __restrict__ offs)
{
  __shared__ int rloc[1024], rlen[1024];
  __shared__ int cnt[256], sc[256];
  const int b = blockIdx.x, t = threadIdx.x;
  const int bb = bases[b];
  const int node0 = b << 8;
  const int nnode = min(256, N - node0);

  for (int k = t; k < C1; k += 512){
    rlen[k] = tcounts[(size_t)b * C1 + k];
    rloc[k] = k * K1E + trunstart[(size_t)b * C1 + k];
  }
  if (t < 256) cnt[t] = 0;
  __syncthreads();
  for (int r = t; r < C1; r += 512){
    const int L = rlen[r], base = rloc[r];
    for (int q = 0; q < L; ++q) atomicAdd(&cnt[temp[base + q] >> 17], 1);
  }
  __syncthreads();
  if (t < 256) sc[t] = cnt[t];
  __syncthreads();
  for (int off = 1; off < 256; off <<= 1){
    int a = (t < 256 && t >= off) ? sc[t - off] : 0;
    __syncthreads();
    if (t < 256) sc[t] += a;
    __syncthreads();
  }
  if (t < 256){
    int ex = sc[t] - cnt[t];
    if (t < nnode) offs[node0 + t] = bb + ex;
    cnt[t] = ex;
  }
  __syncthreads();
  for (int r = t; r < C1; r += 512){
    const int L = rlen[r], base = rloc[r];
    for (int q = 0; q < L; ++q){
      unsigned v = temp[base + q];
      int p = atomicAdd(&cnt[v >> 17], 1);
      ssrc[bb + p] = (int)(v & 0x1FFFFu);
    }
  }
}

// ---------------- fused linear + score kernel (chunk-major fp16 output) ----------------
// hc layout: [FOUT/16][n][16] halves (each 3.2MB-or-less chunk is contiguous)
template<int FIN, int FOUT, typename TIN>
__global__ __launch_bounds__(256) void k_linear(
    const TIN* __restrict__ x, const float* __restrict__ W,
    const float* __restrict__ a_s, const float* __restrict__ a_d,
    __half* __restrict__ hc, float* __restrict__ s_src, float* __restrict__ s_dst, int n)
{
  constexpr bool IN16 = sizeof(TIN) == 2;
  constexpr int CK = IN16 ? 16 : 32;
  constexpr int NCH = FIN / CK;
  __shared__ float xs[CK][257];
  const int tid = threadIdx.x;
  const int node0 = blockIdx.x * 256;
  const int node = node0 + tid;
  const int nrow = min(256, n - node0);

  float acc[FOUT];
#pragma unroll
  for (int o = 0; o < FOUT; ++o) acc[o] = 0.f;

  for (int kc = 0; kc < NCH; ++kc){
    __syncthreads();
    if (!IN16){
      // fp32 node-major input
      const int r0 = tid >> 3;
      const int c4 = tid & 7;
#pragma unroll
      for (int p = 0; p < 8; ++p){
        int row = p * 32 + r0;
        if (row < nrow){
          const float4 v = *reinterpret_cast<const float4*>(
              (const float*)x + (size_t)(node0 + row) * FIN + kc * CK + c4 * 4);
          xs[c4 * 4 + 0][row] = v.x;
          xs[c4 * 4 + 1][row] = v.y;
          xs[c4 * 4 + 2][row] = v.z;
          xs[c4 * 4 + 3][row] = v.w;
        }
      }
    } else {
      // fp16 chunk-major input: chunk kc is x + kc*n*16, row stride 16 halves
      const int r0 = tid >> 1;          // 0..127
      const int u  = tid & 1;           // which 8-half piece
#pragma unroll
      for (int p = 0; p < 2; ++p){
        int row = p * 128 + r0;
        if (row < nrow){
          const uint4 v = *reinterpret_cast<const uint4*>(
              (const __half*)x + (size_t)kc * n * 16 + (size_t)(node0 + row) * 16 + u * 8);
          float2 f0 = upk2(v.x), f1 = upk2(v.y), f2 = upk2(v.z), f3 = upk2(v.w);
          xs[u * 8 + 0][row] = f0.x; xs[u * 8 + 1][row] = f0.y;
          xs[u * 8 + 2][row] = f1.x; xs[u * 8 + 3][row] = f1.y;
          xs[u * 8 + 4][row] = f2.x; xs[u * 8 + 5][row] = f2.y;
          xs[u * 8 + 6][row] = f3.x; xs[u * 8 + 7][row] = f3.y;
        }
      }
    }
    __syncthreads();
#pragma unroll 8
    for (int k = 0; k < CK; ++k){
      float xv = xs[k][tid];
      const int kg = kc * CK + k;
#pragma unroll
      for (int o4 = 0; o4 < FOUT / 4; ++o4){
        const float4 w = *reinterpret_cast<const float4*>(W + (size_t)kg * FOUT + o4 * 4);
        acc[o4 * 4 + 0] = fmaf(xv, w.x, acc[o4 * 4 + 0]);
        acc[o4 * 4 + 1] = fmaf(xv, w.y, acc[o4 * 4 + 1]);
        acc[o4 * 4 + 2] = fmaf(xv, w.z, acc[o4 * 4 + 2]);
        acc[o4 * 4 + 3] = fmaf(xv, w.w, acc[o4 * 4 + 3]);
      }
    }
  }

  if (node < n){
    float vs = 0.f, vd = 0.f;
#pragma unroll
    for (int o4 = 0; o4 < FOUT / 4; ++o4){
      const float4 as = *reinterpret_cast<const float4*>(a_s + o4 * 4);
      const float4 ad = *reinterpret_cast<const float4*>(a_d + o4 * 4);
      vs += acc[o4*4+0]*as.x + acc[o4*4+1]*as.y + acc[o4*4+2]*as.z + acc[o4*4+3]*as.w;
      vd += acc[o4*4+0]*ad.x + acc[o4*4+1]*ad.y + acc[o4*4+2]*ad.z + acc[o4*4+3]*ad.w;
    }
#pragma unroll
    for (int c = 0; c < FOUT / 16; ++c){
      uint4 u0, u1;
      u0.x = pk2(acc[c*16+ 0], acc[c*16+ 1]); u0.y = pk2(acc[c*16+ 2], acc[c*16+ 3]);
      u0.z = pk2(acc[c*16+ 4], acc[c*16+ 5]); u0.w = pk2(acc[c*16+ 6], acc[c*16+ 7]);
      u1.x = pk2(acc[c*16+ 8], acc[c*16+ 9]); u1.y = pk2(acc[c*16+10], acc[c*16+11]);
      u1.z = pk2(acc[c*16+12], acc[c*16+13]); u1.w = pk2(acc[c*16+14], acc[c*16+15]);
      __half* dst = hc + ((size_t)c * n + node) * 16;
      *reinterpret_cast<uint4*>(dst)     = u0;
      *reinterpret_cast<uint4*>(dst + 8) = u1;
    }
    s_src[node] = vs;
    s_dst[node] = vd;
  }
}

// ---------------- per-segment softmax stats + fp16 alpha in CSR order ----------------
__global__ __launch_bounds__(256) void k_score(
    const int* __restrict__ offs, const int* __restrict__ ssrc,
    const float* __restrict__ s_src, const float* __restrict__ s_dst,
    float* __restrict__ gmv, float* __restrict__ invv, __half* __restrict__ w16, int n)
{
  constexpr int CAP = 128;
  __shared__ float ew[4][CAP];
  const int wv = threadIdx.x >> 6;
  const int lane = threadIdx.x & 63;
  const int wid = (blockIdx.x * blockDim.x + threadIdx.x) >> 6;
  const bool act = wid < n;
  int beg = 0, end = 0;
  float sd = 0.f;
  if (act){ beg = offs[wid]; end = offs[wid + 1]; sd = s_dst[wid]; }
  const int deg = end - beg;
  const bool fit = deg <= CAP;            // wave-uniform

  float m = -FLT_MAX, ssum = 0.f;
  for (int j = beg + lane; j < end; j += 64){
    int s = ssrc[j];
    float e = s_src[s] + sd;
    e = (e > 0.f) ? e : 0.2f * e;
    if (fit) ew[wv][j - beg] = e;
    if (e > m){ ssum = ssum * __expf(m - e) + 1.f; m = e; }
    else ssum += __expf(e - m);
  }
  asm volatile("s_waitcnt lgkmcnt(0)" ::: "memory");   // wave-local ew visibility
  float gm = wredmax(m);
  float denom = wredsum(ssum * __expf(m - gm));
  float inv = 1.f / denom;
  if (act && lane == 0){ gmv[wid] = gm; invv[wid] = inv; }

  for (int j = beg + lane; j < end; j += 64){
    float e;
    if (fit) e = ew[wv][j - beg];
    else { e = s_src[ssrc[j]] + sd; e = (e > 0.f) ? e : 0.2f * e; }
    w16[j] = __float2half(__expf(e - gm) * inv);
  }
}

// ---------------- chunked aggregation: out[wid] += sum alpha * hc[src] (16 feats) ----------------
// hc: chunk sub-table [n][16] halves (3.2MB or less -> XCD-L2 resident)
template<typename TOUT, bool ELU>
__global__ __launch_bounds__(256) void k_agg(
    const int* __restrict__ offs, const int* __restrict__ ssrc,
    const __half* __restrict__ w16, const __half* __restrict__ hc,
    const float* __restrict__ bias, TOUT* __restrict__ out, int ostride, int n)
{
  const int lane = threadIdx.x & 63;
  const int wid = (blockIdx.x * blockDim.x + threadIdx.x) >> 6;
  if (wid >= n) return;
  const int beg = offs[wid], end = offs[wid + 1];
  const int es = lane >> 1, fg = lane & 1;   // 32 edge slots, 2 lanes/edge

  __half2 c0 = __float2half2_rn(0.f), c1 = c0, c2 = c0, c3 = c0;
  for (int j = beg; j < end; j += 32){
    int jj = j + es;
    if (jj < end){
      int s = ssrc[jj];
      __half2 w2 = __halves2half2(w16[jj], w16[jj]);
      const uint4 hv = *reinterpret_cast<const uint4*>(hc + (size_t)s * 16 + fg * 8);
      c0 = __hfma2(w2, __builtin_bit_cast(__half2, hv.x), c0);
      c1 = __hfma2(w2, __builtin_bit_cast(__half2, hv.y), c1);
      c2 = __hfma2(w2, __builtin_bit_cast(__half2, hv.z), c2);
      c3 = __hfma2(w2, __builtin_bit_cast(__half2, hv.w), c3);
    }
  }
  float2 p0 = __half22float2(c0), p1 = __half22float2(c1),
         p2 = __half22float2(c2), p3 = __half22float2(c3);
  float a0 = p0.x, a1 = p0.y, a2 = p1.x, a3 = p1.y,
        a4 = p2.x, a5 = p2.y, a6 = p3.x, a7 = p3.y;
#pragma unroll
  for (int mm = 2; mm < 64; mm <<= 1){
    a0 += __shfl_xor(a0, mm, 64); a1 += __shfl_xor(a1, mm, 64);
    a2 += __shfl_xor(a2, mm, 64); a3 += __shfl_xor(a3, mm, 64);
    a4 += __shfl_xor(a4, mm, 64); a5 += __shfl_xor(a5, mm, 64);
    a6 += __shfl_xor(a6, mm, 64); a7 += __shfl_xor(a7, mm, 64);
  }
  if (lane < 2){
    float o[8] = {a0,a1,a2,a3,a4,a5,a6,a7};
#pragma unroll
    for (int q = 0; q < 8; ++q){
      float v = o[q] + bias[fg * 8 + q];
      if (ELU) v = (v > 0.f) ? v : (__expf(v) - 1.f);
      o[q] = v;
    }
    if constexpr (sizeof(TOUT) == 2){
      uint4 u;
      u.x = pk2(o[0], o[1]); u.y = pk2(o[2], o[3]);
      u.z = pk2(o[4], o[5]); u.w = pk2(o[6], o[7]);
      *reinterpret_cast<uint4*>((__half*)out + (size_t)wid * ostride + fg * 8) = u;
    } else {
      float4 w0 = {o[0],o[1],o[2],o[3]}, w1 = {o[4],o[5],o[6],o[7]};
      float* dst = (float*)out + (size_t)wid * ostride + fg * 8;
      *reinterpret_cast<float4*>(dst)     = w0;
      *reinterpret_cast<float4*>(dst + 4) = w1;
    }
  }
}

// ---------------- pack per-node softmax state (coalesced) ----------------
__global__ __launch_bounds__(256) void k_pack(
    const float* __restrict__ ss1, const float* __restrict__ sd1,
    const float* __restrict__ gm1, const float* __restrict__ inv1,
    const float* __restrict__ ss2, const float* __restrict__ sd2,
    const float* __restrict__ gm2, const float* __restrict__ inv2,
    float2* __restrict__ ssp, float4* __restrict__ pkd, int N)
{
  int i = blockIdx.x * blockDim.x + threadIdx.x;
  if (i >= N) return;
  ssp[i] = make_float2(ss1[i], ss2[i]);
  pkd[2 * i]     = make_float4(sd1[i], gm1[i], inv1[i], sd2[i]);
  pkd[2 * i + 1] = make_float4(gm2[i], inv2[i], 0.f, 0.f);
}

// ---------------- alpha in original edge order (4 edges/thread ILP) ----------------
__global__ __launch_bounds__(256) void k_alpha(
    const int* __restrict__ ei, int E0, int total, int G,
    const float2* __restrict__ ssp, const float4* __restrict__ pkd,
    float* __restrict__ a1, float* __restrict__ a2)
{
  const int t = blockIdx.x * blockDim.x + threadIdx.x;
  int sv[4], dv[4];
  bool ok[4];
#pragma unroll
  for (int q = 0; q < 4; ++q){
    int i = t + q * G;
    ok[q] = i < total;
    if (ok[q]){
      if (i < E0){ sv[q] = ei[i]; dv[q] = ei[E0 + i]; }
      else { sv[q] = i - E0; dv[q] = sv[q]; }
    }
  }
  float2 ssv[4]; float4 da[4], db[4];
#pragma unroll
  for (int q = 0; q < 4; ++q){
    if (ok[q]){
      ssv[q] = ssp[sv[q]];
      da[q]  = pkd[2 * dv[q]];
      db[q]  = pkd[2 * dv[q] + 1];
    }
  }
#pragma unroll
  for (int q = 0; q < 4; ++q){
    if (ok[q]){
      int i = t + q * G;
      float e1 = ssv[q].x + da[q].x;
      e1 = (e1 > 0.f) ? e1 : 0.2f * e1;
      a1[i] = __expf(e1 - da[q].y) * da[q].z;
      float e2 = ssv[q].y + da[q].w;
      e2 = (e2 > 0.f) ? e2 : 0.2f * e2;
      a2[i] = __expf(e2 - db[q].x) * db[q].y;
    }
  }
}

// ---------------- launch ----------------
extern "C" void kernel_launch(void* const* d_in, const int* in_sizes, int n_in,
                              void* d_out, int out_size, void* d_ws, size_t ws_size,
                              hipStream_t stream)
{
  const float* x    = (const float*)d_in[0];
  const int*   ei   = (const int*)  d_in[1];
  const float* W1   = (const float*)d_in[2];
  const float* a_s1 = (const float*)d_in[3];
  const float* a_d1 = (const float*)d_in[4];
  const float* b1   = (const float*)d_in[5];
  const float* W2   = (const float*)d_in[6];
  const float* a_s2 = (const float*)d_in[7];
  const float* a_d2 = (const float*)d_in[8];
  const float* b2   = (const float*)d_in[9];

  const int N    = in_sizes[0] / 128;   // 100000 (< 2^17, packing requirement)
  const int E0   = in_sizes[1] / 2;
  const int Etot = E0 + N;
  const int NB   = (N + 255) >> 8;      // 391 buckets
  const int C1   = (Etot + K1E - 1) / K1E;

  float* out_h2 = (float*)d_out;
  float* out_a1 = out_h2 + (size_t)N * 32;
  float* out_a2 = out_a1 + Etot;

  char* wsp = (char*)d_ws; size_t woff = 0;
  auto alloc = [&](size_t bytes)->void*{
    void* p = wsp + woff; woff += (bytes + 255) & ~(size_t)255; return p;
  };
  unsigned* temp     = (unsigned*)alloc((size_t)C1 * K1E * 4);
  int*      tcounts  = (int*)  alloc((size_t)NB * C1 * 4);
  int*      trunstart= (int*)  alloc((size_t)NB * C1 * 4);
  int*      totals   = (int*)  alloc((size_t)(NB + 1) * 4);
  int*      bases    = (int*)  alloc((size_t)(NB + 1) * 4);
  int*      offs     = (int*)  alloc(((size_t)N + 1) * 4);
  int*      ssrc     = (int*)  alloc((size_t)Etot * 4);
  __half*   h1c      = (__half*)alloc((size_t)N * 64 * 2);   // [4][N][16]
  __half*   g1c      = (__half*)alloc((size_t)N * 64 * 2);   // [4][N][16]
  __half*   h2c      = (__half*)alloc((size_t)N * 32 * 2);   // [2][N][16]
  __half*   w16      = (__half*)alloc((size_t)Etot * 2);
  float*    s1s      = (float*)alloc((size_t)N * 4);
  float*    s1d      = (float*)alloc((size_t)N * 4);
  float*    s2s      = (float*)alloc((size_t)N * 4);
  float*    s2d      = (float*)alloc((size_t)N * 4);
  float*    gm1      = (float*)alloc((size_t)N * 4);
  float*    inv1     = (float*)alloc((size_t)N * 4);
  float*    gm2      = (float*)alloc((size_t)N * 4);
  float*    inv2     = (float*)alloc((size_t)N * 4);
  float2*   ssp      = (float2*)alloc((size_t)N * 8);
  float4*   pkd      = (float4*)alloc((size_t)N * 32);

  const int tb = 256;
  k_split<<<C1, 256, 0, stream>>>(ei, E0, Etot, NB, C1, temp, tcounts, trunstart);
  k_rowsum<<<NB, 256, 0, stream>>>(tcounts, C1, totals);
  k_bases2<<<1, 512, 0, stream>>>(totals, NB, Etot, bases, offs, N);
  k_bucket<<<NB, 512, 0, stream>>>(temp, tcounts, trunstart, bases, C1, N, ssrc, offs);

  const int nlb = (N + 255) / 256;
  const int nsb = (N + 3) / 4;

  // layer 1
  k_linear<128, 64, float><<<nlb, 256, 0, stream>>>(x, W1, a_s1, a_d1, h1c, s1s, s1d, N);
  k_score<<<nsb, 256, 0, stream>>>(offs, ssrc, s1s, s1d, gm1, inv1, w16, N);
  for (int c = 0; c < 4; ++c)
    k_agg<__half, true><<<nsb, 256, 0, stream>>>(
        offs, ssrc, w16, h1c + (size_t)c * N * 16, b1 + c * 16,
        g1c + (size_t)c * N * 16, 16, N);

  // layer 2
  k_linear<64, 32, __half><<<nlb, 256, 0, stream>>>(g1c, W2, a_s2, a_d2, h2c, s2s, s2d, N);
  k_score<<<nsb, 256, 0, stream>>>(offs, ssrc, s2s, s2d, gm2, inv2, w16, N);
  for (int c = 0; c < 2; ++c)
    k_agg<float, false><<<nsb, 256, 0, stream>>>(
        offs, ssrc, w16, h2c + (size_t)c * N * 16, b2 + c * 16,
        out_h2 + c * 16, 32, N);

  k_pack<<<nlb, 256, 0, stream>>>(s1s, s1d, gm1, inv1, s2s, s2d, gm2, inv2, ssp, pkd, N);
  const int G = (Etot + 3) / 4;
  k_alpha<<<(G + tb - 1) / tb, tb, 0, stream>>>(ei, E0, Etot, G, ssp, pkd, out_a1, out_a2);
}

// Round 11
// 348.375 us; speedup vs baseline: 1.5056x; 1.5056x over previous
//
#include <hip/hip_runtime.h>
#include <hip/hip_fp16.h>
#include <float.h>

#define K1E 6528   // edges per k_split block (13KB u32 stage + 4KB counters in LDS)

__device__ __forceinline__ float wredmax(float v){
#pragma unroll
  for (int m = 32; m >= 1; m >>= 1) v = fmaxf(v, __shfl_xor(v, m, 64));
  return v;
}
__device__ __forceinline__ float wredsum(float v){
#pragma unroll
  for (int m = 32; m >= 1; m >>= 1) v += __shfl_xor(v, m, 64);
  return v;
}
__device__ __forceinline__ int wredsumi(int v){
#pragma unroll
  for (int m = 32; m >= 1; m >>= 1) v += __shfl_xor(v, m, 64);
  return v;
}
__device__ __forceinline__ unsigned pk2(float a, float b){
  __half2 t = __floats2half2_rn(a, b);
  return __builtin_bit_cast(unsigned, t);
}

// ---------------- CSR build: deterministic two-level counting sort ----------------
__global__ __launch_bounds__(256) void k_split(
    const int* __restrict__ ei, int E0, int total, int NB, int C1,
    unsigned* __restrict__ temp, int* __restrict__ tcounts, int* __restrict__ trunstart)
{
  __shared__ int cnt[512];
  __shared__ int pref[512];
  __shared__ unsigned stage[K1E];
  const int tid = threadIdx.x, blk = blockIdx.x;
  const int lo = blk * K1E, hi = min(lo + K1E, total);

  for (int i = tid; i < 512; i += 256) cnt[i] = 0;
  __syncthreads();
  for (int i = lo + tid; i < hi; i += 256){
    int d = (i < E0) ? ei[E0 + i] : (i - E0);
    atomicAdd(&cnt[d >> 8], 1);
  }
  __syncthreads();
  for (int i = tid; i < 512; i += 256) pref[i] = cnt[i];
  __syncthreads();
  for (int off = 1; off < 512; off <<= 1){
    int a0 = (tid >= off) ? pref[tid - off] : 0;
    int a1 = pref[tid + 256 - off];
    __syncthreads();
    pref[tid] += a0;
    pref[tid + 256] += a1;
    __syncthreads();
  }
  for (int i = tid; i < NB; i += 256){
    int c = cnt[i];
    int ex = pref[i] - c;
    tcounts[(size_t)i * C1 + blk] = c;
    trunstart[(size_t)i * C1 + blk] = ex;
    cnt[i] = ex;
  }
  __syncthreads();
  for (int i = lo + tid; i < hi; i += 256){
    int s, d;
    if (i < E0){ s = ei[i]; d = ei[E0 + i]; } else { s = i - E0; d = s; }
    int p = atomicAdd(&cnt[d >> 8], 1);
    stage[p] = ((unsigned)(d & 255) << 17) | (unsigned)s;
  }
  __syncthreads();
  for (int i = tid; i < hi - lo; i += 256) temp[(size_t)lo + i] = stage[i];
}

__global__ __launch_bounds__(256) void k_rowsum(
    const int* __restrict__ tcounts, int C1, int* __restrict__ totals)
{
  const int b = blockIdx.x;
  const int* row = tcounts + (size_t)b * C1;
  int s = 0;
  for (int k = threadIdx.x; k < C1; k += 256) s += row[k];
  s = wredsumi(s);
  __shared__ int ws[4];
  if ((threadIdx.x & 63) == 0) ws[threadIdx.x >> 6] = s;
  __syncthreads();
  if (threadIdx.x == 0) totals[b] = ws[0] + ws[1] + ws[2] + ws[3];
}

__global__ __launch_bounds__(512) void k_bases2(
    const int* __restrict__ totals, int NB, int total,
    int* __restrict__ bases, int* __restrict__ offs, int N)
{
  __shared__ int sc[512];
  const int t = threadIdx.x;
  int v = (t < NB) ? totals[t] : 0;
  sc[t] = v; __syncthreads();
  for (int off = 1; off < 512; off <<= 1){
    int a = (t >= off) ? sc[t - off] : 0;
    __syncthreads();
    sc[t] += a;
    __syncthreads();
  }
  if (t < NB) bases[t] = sc[t] - v;
  if (t == 0) offs[N] = total;
}

__global__ __launch_bounds__(512) void k_bucket(
    const unsigned* __restrict__ temp, const int* __restrict__ tcounts,
    const int* __restrict__ trunstart, const int* __restrict__ bases,
    int C1, int N, int* __restrict__ ssrc, int* __restrict__ offs)
{
  __shared__ int rloc[1024], rlen[1024];
  __shared__ int cnt[256], sc[256];
  const int b = blockIdx.x, t = threadIdx.x;
  const int bb = bases[b];
  const int node0 = b << 8;
  const int nnode = min(256, N - node0);

  for (int k = t; k < C1; k += 512){
    rlen[k] = tcounts[(size_t)b * C1 + k];
    rloc[k] = k * K1E + trunstart[(size_t)b * C1 + k];
  }
  if (t < 256) cnt[t] = 0;
  __syncthreads();
  for (int r = t; r < C1; r += 512){
    const int L = rlen[r], base = rloc[r];
    for (int q = 0; q < L; ++q) atomicAdd(&cnt[temp[base + q] >> 17], 1);
  }
  __syncthreads();
  if (t < 256) sc[t] = cnt[t];
  __syncthreads();
  for (int off = 1; off < 256; off <<= 1){
    int a = (t < 256 && t >= off) ? sc[t - off] : 0;
    __syncthreads();
    if (t < 256) sc[t] += a;
    __syncthreads();
  }
  if (t < 256){
    int ex = sc[t] - cnt[t];
    if (t < nnode) offs[node0 + t] = bb + ex;
    cnt[t] = ex;
  }
  __syncthreads();
  for (int r = t; r < C1; r += 512){
    const int L = rlen[r], base = rloc[r];
    for (int q = 0; q < L; ++q){
      unsigned v = temp[base + q];
      int p = atomicAdd(&cnt[v >> 17], 1);
      ssrc[bb + p] = (int)(v & 0x1FFFFu);
    }
  }
}

// ---------------- score-projection precompute: wa = W @ a (tiny) ----------------
// wa layout: [0:128)=W1@a_s1, [128:256)=W1@a_d1, [256:320)=W2@a_s2, [320:384)=W2@a_d2
__global__ __launch_bounds__(256) void k_wa(
    const float* __restrict__ W1, const float* __restrict__ as1, const float* __restrict__ ad1,
    const float* __restrict__ W2, const float* __restrict__ as2, const float* __restrict__ ad2,
    float* __restrict__ wa)
{
  int t = threadIdx.x;
  if (t < 128){
    float s = 0.f, d = 0.f;
    for (int o = 0; o < 64; ++o){
      float w = W1[t * 64 + o];
      s = fmaf(w, as1[o], s); d = fmaf(w, ad1[o], d);
    }
    wa[t] = s; wa[128 + t] = d;
  } else if (t < 192){
    int k = t - 128;
    float s = 0.f, d = 0.f;
    for (int o = 0; o < 32; ++o){
      float w = W2[k * 32 + o];
      s = fmaf(w, as2[o], s); d = fmaf(w, ad2[o], d);
    }
    wa[256 + k] = s; wa[320 + k] = d;
  }
}

// ---------------- fused linear + score kernel (FOUT-split, fp16 h output) ----------------
// grid = nlb * S; slice = blockIdx.x % S (fast dim -> adjacent blocks share x window in L2)
template<int FIN, int FOUT, int S>
__global__ __launch_bounds__(256) void k_linear(
    const float* __restrict__ x, const float* __restrict__ W,
    const float* __restrict__ was, const float* __restrict__ wad,
    __half* __restrict__ h16, float* __restrict__ s_src, float* __restrict__ s_dst, int n)
{
  constexpr int FS = FOUT / S;
  constexpr int CK = 32;
  constexpr int NCH = FIN / CK;
  __shared__ float xs[CK][257];
  const int tid = threadIdx.x;
  const int slice = blockIdx.x % S;
  const int node0 = (blockIdx.x / S) * 256;
  const int node = node0 + tid;
  const int nrow = min(256, n - node0);

  float acc[FS];
#pragma unroll
  for (int o = 0; o < FS; ++o) acc[o] = 0.f;
  float vs = 0.f, vd = 0.f;

  for (int kc = 0; kc < NCH; ++kc){
    __syncthreads();
    const int r0 = tid >> 3;
    const int c4 = tid & 7;
#pragma unroll
    for (int p = 0; p < 8; ++p){
      int row = p * 32 + r0;
      if (row < nrow){
        const float4 v = *reinterpret_cast<const float4*>(
            x + (size_t)(node0 + row) * FIN + kc * CK + c4 * 4);
        xs[c4 * 4 + 0][row] = v.x;
        xs[c4 * 4 + 1][row] = v.y;
        xs[c4 * 4 + 2][row] = v.z;
        xs[c4 * 4 + 3][row] = v.w;
      }
    }
    __syncthreads();
#pragma unroll 8
    for (int k = 0; k < CK; ++k){
      float xv = xs[k][tid];
      const int kg = kc * CK + k;
      vs = fmaf(xv, was[kg], vs);
      vd = fmaf(xv, wad[kg], vd);
#pragma unroll
      for (int o4 = 0; o4 < FS / 4; ++o4){
        const float4 w = *reinterpret_cast<const float4*>(
            W + (size_t)kg * FOUT + slice * FS + o4 * 4);
        acc[o4 * 4 + 0] = fmaf(xv, w.x, acc[o4 * 4 + 0]);
        acc[o4 * 4 + 1] = fmaf(xv, w.y, acc[o4 * 4 + 1]);
        acc[o4 * 4 + 2] = fmaf(xv, w.z, acc[o4 * 4 + 2]);
        acc[o4 * 4 + 3] = fmaf(xv, w.w, acc[o4 * 4 + 3]);
      }
    }
  }

  if (node < n){
#pragma unroll
    for (int c = 0; c < FS / 8; ++c){
      uint4 u;
      u.x = pk2(acc[c*8+0], acc[c*8+1]);
      u.y = pk2(acc[c*8+2], acc[c*8+3]);
      u.z = pk2(acc[c*8+4], acc[c*8+5]);
      u.w = pk2(acc[c*8+6], acc[c*8+7]);
      *reinterpret_cast<uint4*>(h16 + (size_t)node * FOUT + slice * FS + c * 8) = u;
    }
    if (slice == 0){ s_src[node] = vs; s_dst[node] = vd; }
  }
}

// ---------------- segment softmax + aggregate (LDS e-cache + dual pk-fma chains) ----------------
template<int F, bool ELU>
__global__ __launch_bounds__(256) void k_segment(
    const int* __restrict__ offs, const int* __restrict__ ssrc,
    const float* __restrict__ s_src, const float* __restrict__ s_dst,
    const __half* __restrict__ h16, const float* __restrict__ bias,
    float* __restrict__ out, float* __restrict__ gmv, float* __restrict__ invv, int n)
{
  constexpr int CAP = 128;
  __shared__ float ew[4][CAP];
  const int wv = threadIdx.x >> 6;
  const int lane = threadIdx.x & 63;
  const int wid = (blockIdx.x * blockDim.x + threadIdx.x) >> 6;
  const bool act = wid < n;
  int beg = 0, end = 0;
  float sd = 0.f;
  if (act){ beg = offs[wid]; end = offs[wid + 1]; sd = s_dst[wid]; }
  const int deg = end - beg;
  const bool fit = deg <= CAP;            // wave-uniform

  // pass A: online (max, scaled-sum); cache post-leaky scores in LDS
  float m = -FLT_MAX, ssum = 0.f;
  for (int j = beg + lane; j < end; j += 64){
    int s = ssrc[j];
    float e = s_src[s] + sd;
    e = (e > 0.f) ? e : 0.2f * e;
    if (fit) ew[wv][j - beg] = e;
    if (e > m){ ssum = ssum * __expf(m - e) + 1.f; m = e; }
    else ssum += __expf(e - m);
  }
  asm volatile("s_waitcnt lgkmcnt(0)" ::: "memory");   // wave-local ew visibility
  float gm = wredmax(m);
  float denom = wredsum(ssum * __expf(m - gm));
  float inv = 1.f / denom;
  if (act && lane == 0){ gmv[wid] = gm; invv[wid] = inv; }

  // pass B: FG lanes per edge (uint4 = 8 halves), 2*ES edges in flight (dual chains)
  constexpr int FG = F / 8;
  constexpr int ES = 64 / FG;
  const int es = lane / FG, fg = lane % FG;
  __half2 hc0 = __float2half2_rn(0.f), hc1 = hc0, hc2 = hc0, hc3 = hc0;
  __half2 hd0 = hc0, hd1 = hc0, hd2 = hc0, hd3 = hc0;
  for (int j = beg; j < end; j += 2 * ES){
    const int j0 = j + es;
    const int j1 = j + ES + es;
    if (j0 < end){
      int s = ssrc[j0];
      float e;
      if (fit) e = ew[wv][j0 - beg];
      else { e = s_src[s] + sd; e = (e > 0.f) ? e : 0.2f * e; }
      float w = __expf(e - gm) * inv;
      __half2 w2 = __float2half2_rn(w);
      const uint4 hv = *reinterpret_cast<const uint4*>(h16 + (size_t)s * F + fg * 8);
      hc0 = __hfma2(w2, __builtin_bit_cast(__half2, hv.x), hc0);
      hc1 = __hfma2(w2, __builtin_bit_cast(__half2, hv.y), hc1);
      hc2 = __hfma2(w2, __builtin_bit_cast(__half2, hv.z), hc2);
      hc3 = __hfma2(w2, __builtin_bit_cast(__half2, hv.w), hc3);
    }
    if (j1 < end){
      int s = ssrc[j1];
      float e;
      if (fit) e = ew[wv][j1 - beg];
      else { e = s_src[s] + sd; e = (e > 0.f) ? e : 0.2f * e; }
      float w = __expf(e - gm) * inv;
      __half2 w2 = __float2half2_rn(w);
      const uint4 hv = *reinterpret_cast<const uint4*>(h16 + (size_t)s * F + fg * 8);
      hd0 = __hfma2(w2, __builtin_bit_cast(__half2, hv.x), hd0);
      hd1 = __hfma2(w2, __builtin_bit_cast(__half2, hv.y), hd1);
      hd2 = __hfma2(w2, __builtin_bit_cast(__half2, hv.z), hd2);
      hd3 = __hfma2(w2, __builtin_bit_cast(__half2, hv.w), hd3);
    }
  }
  hc0 = __hadd2(hc0, hd0); hc1 = __hadd2(hc1, hd1);
  hc2 = __hadd2(hc2, hd2); hc3 = __hadd2(hc3, hd3);
  float2 p0 = __half22float2(hc0), p1 = __half22float2(hc1),
         p2 = __half22float2(hc2), p3 = __half22float2(hc3);
  float a0 = p0.x, a1 = p0.y, a2 = p1.x, a3 = p1.y,
        a4 = p2.x, a5 = p2.y, a6 = p3.x, a7 = p3.y;
#pragma unroll
  for (int mm = FG; mm < 64; mm <<= 1){
    a0 += __shfl_xor(a0, mm, 64); a1 += __shfl_xor(a1, mm, 64);
    a2 += __shfl_xor(a2, mm, 64); a3 += __shfl_xor(a3, mm, 64);
    a4 += __shfl_xor(a4, mm, 64); a5 += __shfl_xor(a5, mm, 64);
    a6 += __shfl_xor(a6, mm, 64); a7 += __shfl_xor(a7, mm, 64);
  }
  if (act && lane < FG){
    float o[8] = {a0,a1,a2,a3,a4,a5,a6,a7};
#pragma unroll
    for (int q = 0; q < 8; ++q){
      float v = o[q] + bias[fg * 8 + q];
      if (ELU) v = (v > 0.f) ? v : (__expf(v) - 1.f);
      o[q] = v;
    }
    float4 w0 = {o[0],o[1],o[2],o[3]}, w1 = {o[4],o[5],o[6],o[7]};
    *reinterpret_cast<float4*>(out + (size_t)wid * F + fg * 8)     = w0;
    *reinterpret_cast<float4*>(out + (size_t)wid * F + fg * 8 + 4) = w1;
  }
}

// ---------------- fp32->fp16 recast for layer-2 input is avoided: g1 stays fp32 ----------------
// (layer-2 k_linear reads g1 fp32; only the gathered h tables are fp16)

// ---------------- pack per-node softmax state (coalesced) ----------------
__global__ __launch_bounds__(256) void k_pack(
    const float* __restrict__ ss1, const float* __restrict__ sd1,
    const float* __restrict__ gm1, const float* __restrict__ inv1,
    const float* __restrict__ ss2, const float* __restrict__ sd2,
    const float* __restrict__ gm2, const float* __restrict__ inv2,
    float2* __restrict__ ssp, float4* __restrict__ pkd, int N)
{
  int i = blockIdx.x * blockDim.x + threadIdx.x;
  if (i >= N) return;
  ssp[i] = make_float2(ss1[i], ss2[i]);
  pkd[2 * i]     = make_float4(sd1[i], gm1[i], inv1[i], sd2[i]);
  pkd[2 * i + 1] = make_float4(gm2[i], inv2[i], 0.f, 0.f);
}

// ---------------- alpha in original edge order (4 edges/thread ILP) ----------------
__global__ __launch_bounds__(256) void k_alpha(
    const int* __restrict__ ei, int E0, int total, int G,
    const float2* __restrict__ ssp, const float4* __restrict__ pkd,
    float* __restrict__ a1, float* __restrict__ a2)
{
  const int t = blockIdx.x * blockDim.x + threadIdx.x;
  int sv[4], dv[4];
  bool ok[4];
#pragma unroll
  for (int q = 0; q < 4; ++q){
    int i = t + q * G;
    ok[q] = i < total;
    if (ok[q]){
      if (i < E0){ sv[q] = ei[i]; dv[q] = ei[E0 + i]; }
      else { sv[q] = i - E0; dv[q] = sv[q]; }
    }
  }
  float2 ssv[4]; float4 da[4], db[4];
#pragma unroll
  for (int q = 0; q < 4; ++q){
    if (ok[q]){
      ssv[q] = ssp[sv[q]];
      da[q]  = pkd[2 * dv[q]];
      db[q]  = pkd[2 * dv[q] + 1];
    }
  }
#pragma unroll
  for (int q = 0; q < 4; ++q){
    if (ok[q]){
      int i = t + q * G;
      float e1 = ssv[q].x + da[q].x;
      e1 = (e1 > 0.f) ? e1 : 0.2f * e1;
      a1[i] = __expf(e1 - da[q].y) * da[q].z;
      float e2 = ssv[q].y + da[q].w;
      e2 = (e2 > 0.f) ? e2 : 0.2f * e2;
      a2[i] = __expf(e2 - db[q].x) * db[q].y;
    }
  }
}

// ---------------- launch ----------------
extern "C" void kernel_launch(void* const* d_in, const int* in_sizes, int n_in,
                              void* d_out, int out_size, void* d_ws, size_t ws_size,
                              hipStream_t stream)
{
  const float* x    = (const float*)d_in[0];
  const int*   ei   = (const int*)  d_in[1];
  const float* W1   = (const float*)d_in[2];
  const float* a_s1 = (const float*)d_in[3];
  const float* a_d1 = (const float*)d_in[4];
  const float* b1   = (const float*)d_in[5];
  const float* W2   = (const float*)d_in[6];
  const float* a_s2 = (const float*)d_in[7];
  const float* a_d2 = (const float*)d_in[8];
  const float* b2   = (const float*)d_in[9];

  const int N    = in_sizes[0] / 128;   // 100000 (< 2^17, packing requirement)
  const int E0   = in_sizes[1] / 2;
  const int Etot = E0 + N;
  const int NB   = (N + 255) >> 8;      // 391 buckets
  const int C1   = (Etot + K1E - 1) / K1E;

  float* out_h2 = (float*)d_out;
  float* out_a1 = out_h2 + (size_t)N * 32;
  float* out_a2 = out_a1 + Etot;

  char* wsp = (char*)d_ws; size_t woff = 0;
  auto alloc = [&](size_t bytes)->void*{
    void* p = wsp + woff; woff += (bytes + 255) & ~(size_t)255; return p;
  };
  unsigned* temp     = (unsigned*)alloc((size_t)C1 * K1E * 4);
  int*      tcounts  = (int*)  alloc((size_t)NB * C1 * 4);
  int*      trunstart= (int*)  alloc((size_t)NB * C1 * 4);
  int*      totals   = (int*)  alloc((size_t)(NB + 1) * 4);
  int*      bases    = (int*)  alloc((size_t)(NB + 1) * 4);
  int*      offs     = (int*)  alloc(((size_t)N + 1) * 4);
  int*      ssrc     = (int*)  alloc((size_t)Etot * 4);
  __half*   h1       = (__half*)alloc((size_t)N * 64 * 2);
  float*    g1       = (float*)alloc((size_t)N * 64 * 4);
  __half*   h2l      = (__half*)alloc((size_t)N * 32 * 2);
  float*    wa       = (float*)alloc(384 * 4);
  float*    s1s      = (float*)alloc((size_t)N * 4);
  float*    s1d      = (float*)alloc((size_t)N * 4);
  float*    s2s      = (float*)alloc((size_t)N * 4);
  float*    s2d      = (float*)alloc((size_t)N * 4);
  float*    gm1      = (float*)alloc((size_t)N * 4);
  float*    inv1     = (float*)alloc((size_t)N * 4);
  float*    gm2      = (float*)alloc((size_t)N * 4);
  float*    inv2     = (float*)alloc((size_t)N * 4);
  float2*   ssp      = (float2*)alloc((size_t)N * 8);
  float4*   pkd      = (float4*)alloc((size_t)N * 32);

  const int tb = 256;
  k_split<<<C1, 256, 0, stream>>>(ei, E0, Etot, NB, C1, temp, tcounts, trunstart);
  k_rowsum<<<NB, 256, 0, stream>>>(tcounts, C1, totals);
  k_bases2<<<1, 512, 0, stream>>>(totals, NB, Etot, bases, offs, N);
  k_bucket<<<NB, 512, 0, stream>>>(temp, tcounts, trunstart, bases, C1, N, ssrc, offs);

  k_wa<<<1, 256, 0, stream>>>(W1, a_s1, a_d1, W2, a_s2, a_d2, wa);

  const int nlb = (N + 255) / 256;
  const int nsb = (N + 3) / 4;

  k_linear<128, 64, 2><<<nlb * 2, 256, 0, stream>>>(x, W1, wa, wa + 128, h1, s1s, s1d, N);
  k_segment<64, true><<<nsb, 256, 0, stream>>>(offs, ssrc, s1s, s1d, h1, b1, g1, gm1, inv1, N);
  k_linear<64, 32, 2><<<nlb * 2, 256, 0, stream>>>(g1, W2, wa + 256, wa + 320, h2l, s2s, s2d, N);
  k_segment<32, false><<<nsb, 256, 0, stream>>>(offs, ssrc, s2s, s2d, h2l, b2, out_h2, gm2, inv2, N);

  k_pack<<<nlb, 256, 0, stream>>>(s1s, s1d, gm1, inv1, s2s, s2d, gm2, inv2, ssp, pkd, N);
  const int G = (Etot + 3) / 4;
  k_alpha<<<(G + tb - 1) / tb, tb, 0, stream>>>(ei, E0, Etot, G, ssp, pkd, out_a1, out_a2);
}